// Round 9
// baseline (107.635 us; speedup 1.0000x reference)
//
#include <hip/hip_runtime.h>

#define BTOT 1000000

typedef _Float16 f16;
typedef f16 f16x2 __attribute__((ext_vector_type(2)));
typedef f16 f16x8 __attribute__((ext_vector_type(8)));
typedef float f32x2 __attribute__((ext_vector_type(2)));
typedef float f32x4 __attribute__((ext_vector_type(4)));

// d_ws layout (bytes) — written by setup_kernel, read coalesced by netc_kernel:
//   0     : float u_tgt
//   16    : afragT[8][64]  f16x8   (8192 B)   item = mt*2+ks  (A = W2 rows)
//   8208  : w1aT [8][64]   f16x2   (2048 B)
//   10256 : w1bT [8][64]   f16x2   (2048 B)
//   12304 : b1pT [8][64]   f16x2   (2048 B)
//   14352 : w3q4T[4][64]   float4  (4096 B)   w3 for neurons 16mt+4q+r
//   18448 : b2q4T[4][64]   float4  (4096 B)   b2 for neurons 16mt+4q+r
#define WS_AFRAG 16
#define WS_W1A   8208
#define WS_W1B   10256
#define WS_B1P   12304
#define WS_W3Q   14352
#define WS_B2Q   18448

// One block. Stages W2 coalesced through padded LDS (conflict-free reads),
// computes u(target) once, emits per-lane register images into ws.
__global__ __launch_bounds__(256) void setup_kernel(
    const float* __restrict__ W1, const float* __restrict__ b1,
    const float* __restrict__ W2, const float* __restrict__ b2,
    const float* __restrict__ W3, unsigned char* __restrict__ ws)
{
    const int tid  = threadIdx.x;
    const int quad = (tid & 63) >> 4;
    const int nl   = tid & 15;

    __shared__ float w2s[64 * 65];   // padded: row stride 65 -> conflict-free
    __shared__ float h1s[64];
    __shared__ float part[4 * 64];

    const float4* W2v = (const float4*)W2;
    #pragma unroll
    for (int r = 0; r < 4; ++r) {
        int idx = r * 256 + tid;           // 1024 float4s total
        float4 f = W2v[idx];
        int g = idx * 4, row = g >> 6, col = g & 63;
        float* p = &w2s[row * 65 + col];
        p[0] = f.x; p[1] = f.y; p[2] = f.z; p[3] = f.w;
    }
    const float T = 6.2562059f;  // 0.62562059 * 10
    if (tid < 64)
        h1s[tid] = fmaxf(0.f, W1[2 * tid] * T + W1[2 * tid + 1] * T + b1[tid]);
    __syncthreads();

    {
        int r = tid & 63, kq = tid >> 6;
        float p = 0.f;
        #pragma unroll
        for (int k = 0; k < 16; ++k)
            p = fmaf(w2s[r * 65 + kq * 16 + k], h1s[kq * 16 + k], p);
        part[kq * 64 + r] = p;
    }
    __syncthreads();
    if (tid < 64) {
        float h2 = b2[tid] + part[tid] + part[64 + tid] + part[128 + tid] + part[192 + tid];
        float pr = fmaxf(0.f, h2) * W3[tid];
        #pragma unroll
        for (int m = 1; m < 64; m <<= 1) pr += __shfl_xor(pr, m, 64);
        if (tid == 0) *(float*)ws = pr;
    }

    if (tid < 64) {   // lane = tid: build this lane's register images
        f16x8* afragT = (f16x8*)(ws + WS_AFRAG);
        #pragma unroll
        for (int mt = 0; mt < 4; ++mt)
            #pragma unroll
            for (int ks = 0; ks < 2; ++ks) {
                f16x8 f;
                #pragma unroll
                for (int j = 0; j < 8; ++j)
                    f[j] = (f16)w2s[(mt * 16 + nl) * 65 + ks * 32 + quad * 8 + j];
                afragT[(mt * 2 + ks) * 64 + tid] = f;
            }
        f16x2* w1aT = (f16x2*)(ws + WS_W1A);
        f16x2* w1bT = (f16x2*)(ws + WS_W1B);
        f16x2* b1pT = (f16x2*)(ws + WS_B1P);
        #pragma unroll
        for (int i = 0; i < 8; ++i) {
            int kk = (i < 4) ? (quad * 8 + 2 * i) : (32 + quad * 8 + 2 * (i - 4));
            w1aT[i * 64 + tid] = f16x2{(f16)W1[2 * kk],     (f16)W1[2 * kk + 2]};
            w1bT[i * 64 + tid] = f16x2{(f16)W1[2 * kk + 1], (f16)W1[2 * kk + 3]};
            b1pT[i * 64 + tid] = f16x2{(f16)b1[kk],         (f16)b1[kk + 1]};
        }
        float4* w3q4T = (float4*)(ws + WS_W3Q);
        float4* b2q4T = (float4*)(ws + WS_B2Q);
        #pragma unroll
        for (int mt = 0; mt < 4; ++mt) {
            int nb = mt * 16 + quad * 4;   // neurons nb..nb+3
            w3q4T[mt * 64 + tid] = float4{W3[nb], W3[nb + 1], W3[nb + 2], W3[nb + 3]};
            b2q4T[mt * 64 + tid] = float4{b2[nb], b2[nb + 1], b2[nb + 2], b2[nb + 3]};
        }
    }
}

// (256,4): R6's proven register regime. Swapped GEMM: A = W2 (neurons = M),
// B = layer-1 activations (elements = N = D columns) -> layer-3 reduction is
// 16 in-lane fmas + a 4-wide LDS transpose (no DPP chains, no final bpermute).
__global__ __launch_bounds__(256, 4) void netc_kernel(
    const float* __restrict__ x,  const float* __restrict__ y,
    const float* __restrict__ ex, const float* __restrict__ ey,
    const unsigned char* __restrict__ ws,
    float* __restrict__ out)
{
    const int tid  = threadIdx.x;
    const int lane = tid & 63;
    const int wv   = tid >> 6;
    const int quad = lane >> 4;
    const int nl   = lane & 15;

    __shared__ float red[1024];          // [wv][q'][nl][g] transpose pad, 4 KB
    const int wbase = wv << 8;
    const int waddr = wbase + (lane << 2);          // write slot base (+g)
    const int rbase = wbase + (nl << 2) + quad;     // read slot base (+64*q')

    // ---------- preamble: fully-coalesced ws loads ----------
    const float u_tgt = *(const float*)ws;
    const float one_minus_ut = 1.0f - u_tgt;
    const f16x8* afragT = (const f16x8*)(ws + WS_AFRAG);
    f16x8 afrag[4][2];
    #pragma unroll
    for (int mt = 0; mt < 4; ++mt)
        #pragma unroll
        for (int ks = 0; ks < 2; ++ks)
            afrag[mt][ks] = afragT[(mt * 2 + ks) * 64 + lane];
    const f16x2* w1aT = (const f16x2*)(ws + WS_W1A);
    const f16x2* w1bT = (const f16x2*)(ws + WS_W1B);
    const f16x2* b1pT = (const f16x2*)(ws + WS_B1P);
    f16x2 w1a[8], w1b[8], b1p[8];
    #pragma unroll
    for (int i = 0; i < 8; ++i) {
        w1a[i] = w1aT[i * 64 + lane];
        w1b[i] = w1bT[i * 64 + lane];
        b1p[i] = b1pT[i * 64 + lane];
    }
    const f32x4* w3q4T = (const f32x4*)(ws + WS_W3Q);
    const f32x4* b2q4T = (const f32x4*)(ws + WS_B2Q);
    f32x4 w3q4[4], b2q4[4];
    #pragma unroll
    for (int mt = 0; mt < 4; ++mt) {
        w3q4[mt] = w3q4T[mt * 64 + lane];
        b2q4[mt] = b2q4T[mt * 64 + lane];
    }

    const f16x2 zero2 = {(f16)0.f, (f16)0.f};
    const int nwaves = (gridDim.x * blockDim.x) >> 6;   // 4096
    const int estep  = nwaves << 6;

    int e0 = (((blockIdx.x << 2) + wv) << 6) + lane;

    // double-buffered input registers; loads stay in flight 2 loop bodies
    float axv = 0.f, ayv = 0.f, aexv = 0.f, aeyv = 0.f;
    float bxv = 0.f, byv = 0.f, bexv = 0.f, beyv = 0.f;
    if (e0 < BTOT)         { axv = x[e0]; ayv = y[e0]; aexv = ex[e0]; aeyv = ey[e0]; }
    if (e0 + estep < BTOT) { int p = e0 + estep; bxv = x[p]; byv = y[p]; bexv = ex[p]; beyv = ey[p]; }

    auto body = [&](int ee, float& rx, float& ry, float& rex, float& rey) {
        // consume buffer (issued 2 bodies ago -> arrived), then refill it
        float cx = rx, cy = ry, cex = rex, cey = rey;
        int pe = ee + 2 * estep;
        if (pe < BTOT) { rx = x[pe]; ry = y[pe]; rex = ex[pe]; rey = ey[pe]; }

        float av = cx + cex, bv = cy + cey;
        f16x2 pab = {(f16)av, (f16)bv};
        int pv = __builtin_bit_cast(int, pab);

        // Hill math early — dy needs no u -> store now
        float xs = cx * 0.1f, ys = cy * 0.1f;
        float x2 = xs * xs, y2 = ys * ys;
        float invx = __fdividef(1.0f, 0.25f + x2);
        float invy = __fdividef(1.0f, 0.25f + y2);
        float hx = x2 * invx, hy = y2 * invy;
        float gx = 0.25f * invx, gy = 0.25f * invy;
        float cdx = 10.f * hx;
        float base_dx = fmaf(cdx, one_minus_ut, fmaf(2.f, gy, -11.f * xs));
        float dy = fmaf(10.f, hy, fmaf(2.f, gx, -11.f * ys));
        out[BTOT + ee]     = dy;
        out[3 * BTOT + ee] = -dy;

        // per element-group g (elements ee_base + 16g + nl = D columns):
        #pragma unroll
        for (int g = 0; g < 4; ++g) {
            // this lane's column-element input pair
            f16x2 ab = __builtin_bit_cast(f16x2,
                __builtin_amdgcn_ds_bpermute((g << 6) + (nl << 2), pv));

            // layer 1 -> B-fragments (lane holds h1[k=quad*8+j(+32)] of its column)
            f16x2 a2 = {ab[0], ab[0]};
            f16x2 bb = {ab[1], ab[1]};
            union { f16x2 h2[8]; f16x8 fr[2]; } u;
            #pragma unroll
            for (int i = 0; i < 8; ++i) {
                f16x2 h = a2 * w1a[i] + (bb * w1b[i] + b1p[i]);
                u.h2[i] = __builtin_elementwise_max(h, zero2);
            }

            // layer 2: D[mt] = W2 * h1 + b2 (b2 folded as C operand, D != C)
            f32x4 acc[4];
            #pragma unroll
            for (int mt = 0; mt < 4; ++mt) {
                acc[mt] = __builtin_amdgcn_mfma_f32_16x16x32_f16(afrag[mt][0], u.fr[0], b2q4[mt], 0, 0, 0);
                acc[mt] = __builtin_amdgcn_mfma_f32_16x16x32_f16(afrag[mt][1], u.fr[1], acc[mt], 0, 0, 0);
            }

            // layer 3 (in-lane): s = sum_{mt,r} relu(acc)*w3  (16 neurons/lane)
            f32x2 s01 = {0.f, 0.f}, s23 = {0.f, 0.f};
            #pragma unroll
            for (int mt = 0; mt < 4; ++mt) {
                f32x4 rel = __builtin_elementwise_max(acc[mt], f32x4{0.f, 0.f, 0.f, 0.f});
                f32x2 lo = {rel[0], rel[1]}, hi = {rel[2], rel[3]};
                f32x2 wlo = {w3q4[mt][0], w3q4[mt][1]}, whi = {w3q4[mt][2], w3q4[mt][3]};
                s01 += lo * wlo;
                s23 += hi * whi;
            }
            f32x2 s2 = s01 + s23;
            red[waddr + g] = s2[0] + s2[1];   // partial: neurons [16mt+4q+r] of elem 16g+nl
        }

        // cross-quad sum via LDS transpose (same-wave DS is in-order; 2-way banks)
        float u_raw = red[rbase] + red[rbase + 64] + red[rbase + 128] + red[rbase + 192];

        float dx = fmaf(cdx, u_raw, base_dx);
        out[ee]            = dx;
        out[2 * BTOT + ee] = -dx;
    };

    for (int e = e0; e < BTOT; e += 2 * estep) {
        body(e, axv, ayv, aexv, aeyv);
        int e1 = e + estep;
        if (e1 < BTOT)
            body(e1, bxv, byv, bexv, beyv);
    }
}

extern "C" void kernel_launch(void* const* d_in, const int* in_sizes, int n_in,
                              void* d_out, int out_size, void* d_ws, size_t ws_size,
                              hipStream_t stream) {
    const float* x  = (const float*)d_in[0];
    const float* y  = (const float*)d_in[1];
    const float* ex = (const float*)d_in[2];
    const float* ey = (const float*)d_in[3];
    const float* W1 = (const float*)d_in[4];
    const float* b1 = (const float*)d_in[5];
    const float* W2 = (const float*)d_in[6];
    const float* b2 = (const float*)d_in[7];
    const float* W3 = (const float*)d_in[8];
    float* out = (float*)d_out;
    unsigned char* ws = (unsigned char*)d_ws;

    setup_kernel<<<1, 256, 0, stream>>>(W1, b1, W2, b2, W3, ws);
    // 1024 blocks x 4 waves = 4 blocks/CU resident, grid-stride (R6 assignment)
    netc_kernel<<<1024, 256, 0, stream>>>(x, y, ex, ey, ws, out);
}

// Round 10
// 103.709 us; speedup vs baseline: 1.0379x; 1.0379x over previous
//
#include <hip/hip_runtime.h>

#define BTOT 1000000
#define NCHUNK (BTOT / 64)   // 15625 chunks of 64 elements

typedef _Float16 f16;
typedef f16 f16x2 __attribute__((ext_vector_type(2)));
typedef f16 f16x8 __attribute__((ext_vector_type(8)));
typedef float f32x2 __attribute__((ext_vector_type(2)));
typedef float f32x4 __attribute__((ext_vector_type(4)));

// d_ws layout (bytes) — written by setup_kernel, read coalesced by netc_kernel:
//   0     : float u_tgt
//   16    : bfragT[8][64]  f16x8   (8192 B)   item = n*2+ks
//   8208  : w1aT [8][64]   f16x2   (2048 B)
//   10256 : w1bT [8][64]   f16x2   (2048 B)
//   12304 : b1pT [8][64]   f16x2   (2048 B)
//   14352 : w3vT [4][64]   float   (1024 B)
//   15376 : b2vT [4][64]   float   (1024 B)
#define WS_BFRAG 16
#define WS_W1A   8208
#define WS_W1B   10256
#define WS_B1P   12304
#define WS_W3V   14352
#define WS_B2V   15376

// 16-lane-row rotate-and-add via DPP (VALU pipe, no LDS traffic).
template<int CTRL>
__device__ __forceinline__ float dpp_add(float v) {
    int pv = __builtin_amdgcn_update_dpp(0, __builtin_bit_cast(int, v),
                                         CTRL, 0xF, 0xF, true);
    return v + __builtin_bit_cast(float, pv);
}
__device__ __forceinline__ float row_reduce16(float p) {
    p = dpp_add<0x128>(p);  // row_ror:8
    p = dpp_add<0x124>(p);  // row_ror:4
    p = dpp_add<0x122>(p);  // row_ror:2
    p = dpp_add<0x121>(p);  // row_ror:1
    return p;
}

// One block. Stages W2 coalesced through padded LDS (conflict-free reads),
// computes u(target) once, emits per-lane register images into ws.
__global__ __launch_bounds__(256) void setup_kernel(
    const float* __restrict__ W1, const float* __restrict__ b1,
    const float* __restrict__ W2, const float* __restrict__ b2,
    const float* __restrict__ W3, unsigned char* __restrict__ ws)
{
    const int tid  = threadIdx.x;
    const int quad = (tid & 63) >> 4;
    const int nl   = tid & 15;

    __shared__ float w2s[64 * 65];   // padded: row stride 65 -> conflict-free
    __shared__ float h1s[64];
    __shared__ float part[4 * 64];

    const float4* W2v = (const float4*)W2;
    #pragma unroll
    for (int r = 0; r < 4; ++r) {
        int idx = r * 256 + tid;           // 1024 float4s total
        float4 f = W2v[idx];
        int g = idx * 4, row = g >> 6, col = g & 63;
        float* p = &w2s[row * 65 + col];
        p[0] = f.x; p[1] = f.y; p[2] = f.z; p[3] = f.w;
    }
    const float T = 6.2562059f;  // 0.62562059 * 10
    if (tid < 64)
        h1s[tid] = fmaxf(0.f, W1[2 * tid] * T + W1[2 * tid + 1] * T + b1[tid]);
    __syncthreads();

    {
        int r = tid & 63, kq = tid >> 6;
        float p = 0.f;
        #pragma unroll
        for (int k = 0; k < 16; ++k)
            p = fmaf(w2s[r * 65 + kq * 16 + k], h1s[kq * 16 + k], p);
        part[kq * 64 + r] = p;
    }
    __syncthreads();
    if (tid < 64) {
        float h2 = b2[tid] + part[tid] + part[64 + tid] + part[128 + tid] + part[192 + tid];
        float pr = fmaxf(0.f, h2) * W3[tid];
        #pragma unroll
        for (int m = 1; m < 64; m <<= 1) pr += __shfl_xor(pr, m, 64);
        if (tid == 0) *(float*)ws = pr;
    }

    if (tid < 64) {   // lane = tid: build this lane's register images
        f16x8* bfragT = (f16x8*)(ws + WS_BFRAG);
        #pragma unroll
        for (int n = 0; n < 4; ++n)
            #pragma unroll
            for (int ks = 0; ks < 2; ++ks) {
                f16x8 f;
                #pragma unroll
                for (int j = 0; j < 8; ++j)
                    f[j] = (f16)w2s[(n * 16 + nl) * 65 + ks * 32 + quad * 8 + j];
                bfragT[(n * 2 + ks) * 64 + tid] = f;
            }
        f16x2* w1aT = (f16x2*)(ws + WS_W1A);
        f16x2* w1bT = (f16x2*)(ws + WS_W1B);
        f16x2* b1pT = (f16x2*)(ws + WS_B1P);
        #pragma unroll
        for (int i = 0; i < 8; ++i) {
            int kk = (i < 4) ? (quad * 8 + 2 * i) : (32 + quad * 8 + 2 * (i - 4));
            w1aT[i * 64 + tid] = f16x2{(f16)W1[2 * kk],     (f16)W1[2 * kk + 2]};
            w1bT[i * 64 + tid] = f16x2{(f16)W1[2 * kk + 1], (f16)W1[2 * kk + 3]};
            b1pT[i * 64 + tid] = f16x2{(f16)b1[kk],         (f16)b1[kk + 1]};
        }
        float* w3vT = (float*)(ws + WS_W3V);
        float* b2vT = (float*)(ws + WS_B2V);
        #pragma unroll
        for (int n = 0; n < 4; ++n) {
            w3vT[n * 64 + tid] = W3[n * 16 + nl];
            b2vT[n * 64 + tid] = b2[n * 16 + nl];
        }
    }
}

// (256,4): R6's proven regime. ONE change vs R6: each wave has <=4 bodies,
// so ALL inputs (16 dwords) are loaded up front — zero in-loop loads, no
// dbuf bookkeeping; load latency paid once per wave, overlapped with the
// ws preamble.
__global__ __launch_bounds__(256, 4) void netc_kernel(
    const float* __restrict__ x,  const float* __restrict__ y,
    const float* __restrict__ ex, const float* __restrict__ ey,
    const unsigned char* __restrict__ ws,
    float* __restrict__ out)
{
    const int tid  = threadIdx.x;
    const int lane = tid & 63;
    const int wv   = tid >> 6;
    const int quad = lane >> 4;
    const int nl   = lane & 15;

    const int w  = (blockIdx.x << 2) + wv;      // wave id 0..4095
    const int e0 = (w << 6) + lane;
    const int estep = 4096 << 6;                // 262144

    // ---------- load ALL bodies' inputs first (all 16 in flight) ----------
    float vx[4], vy[4], vex[4], vey[4];
    #pragma unroll
    for (int k = 0; k < 4; ++k) {
        vx[k] = 0.f; vy[k] = 0.f; vex[k] = 0.f; vey[k] = 0.f;
        if (w + k * 4096 < NCHUNK) {   // wave-uniform (chunk-aligned)
            int e = e0 + k * estep;
            vx[k] = x[e]; vy[k] = y[e]; vex[k] = ex[e]; vey[k] = ey[e];
        }
    }

    // ---------- preamble: fully-coalesced ws loads ----------
    const float u_tgt = *(const float*)ws;
    const float one_minus_ut = 1.0f - u_tgt;
    const f16x8* bfragT = (const f16x8*)(ws + WS_BFRAG);
    f16x8 bfrag[4][2];
    #pragma unroll
    for (int n = 0; n < 4; ++n)
        #pragma unroll
        for (int ks = 0; ks < 2; ++ks)
            bfrag[n][ks] = bfragT[(n * 2 + ks) * 64 + lane];
    const f16x2* w1aT = (const f16x2*)(ws + WS_W1A);
    const f16x2* w1bT = (const f16x2*)(ws + WS_W1B);
    const f16x2* b1pT = (const f16x2*)(ws + WS_B1P);
    f16x2 w1a[8], w1b[8], b1p[8];
    #pragma unroll
    for (int i = 0; i < 8; ++i) {
        w1a[i] = w1aT[i * 64 + lane];
        w1b[i] = w1bT[i * 64 + lane];
        b1p[i] = b1pT[i * 64 + lane];
    }
    const float* w3vT = (const float*)(ws + WS_W3V);
    const float* b2vT = (const float*)(ws + WS_B2V);
    float w3v[4], b2v[4];
    #pragma unroll
    for (int n = 0; n < 4; ++n) { w3v[n] = w3vT[n * 64 + lane]; b2v[n] = b2vT[n * 64 + lane]; }

    const f16x2 zero2 = {(f16)0.f, (f16)0.f};
    const int srcb = (((nl >> 2) << 4) + quad * 4 + (nl & 3)) << 2;

    #pragma unroll
    for (int k = 0; k < 4; ++k) {
        if (w + k * 4096 >= NCHUNK) break;     // wave-uniform
        const int e = e0 + k * estep;
        const float cx = vx[k], cy = vy[k];

        float av = cx + vex[k], bv = cy + vey[k];
        f16x2 pab = {(f16)av, (f16)bv};
        int pv = __builtin_bit_cast(int, pab);

        // Hill math early — dy needs no u -> store now
        float xs = cx * 0.1f, ys = cy * 0.1f;
        float x2 = xs * xs, y2 = ys * ys;
        float invx = __fdividef(1.0f, 0.25f + x2);
        float invy = __fdividef(1.0f, 0.25f + y2);
        float hx = x2 * invx, hy = y2 * invy;
        float gx = 0.25f * invx, gy = 0.25f * invy;
        float cdx = 10.f * hx;
        float base_dx = fmaf(cdx, one_minus_ut, fmaf(2.f, gy, -11.f * xs));
        float dy = fmaf(10.f, hy, fmaf(2.f, gx, -11.f * ys));
        out[BTOT + e]     = dy;
        out[3 * BTOT + e] = -dy;

        // distribute A-pairs: tile t gets element e_base + t*16 + nl
        f16x2 pt[4];
        #pragma unroll
        for (int t = 0; t < 4; ++t)
            pt[t] = __builtin_bit_cast(f16x2,
                __builtin_amdgcn_ds_bpermute((t * 16 + nl) << 2, pv));

        float ur[4];
        #pragma unroll
        for (int t = 0; t < 4; ++t) {
            // acc init with b2 (per-tile: only 16 live acc regs)
            f32x4 acc[4];
            #pragma unroll
            for (int n = 0; n < 4; ++n)
                acc[n] = f32x4{b2v[n], b2v[n], b2v[n], b2v[n]};

            f16x2 a2 = {pt[t][0], pt[t][0]};
            f16x2 bb = {pt[t][1], pt[t][1]};
            union { f16x2 h2[8]; f16x8 fr[2]; } u;
            #pragma unroll
            for (int i = 0; i < 8; ++i) {
                f16x2 h = a2 * w1a[i] + (bb * w1b[i] + b1p[i]);
                u.h2[i] = __builtin_elementwise_max(h, zero2);
            }
            #pragma unroll
            for (int n = 0; n < 4; ++n) {
                acc[n] = __builtin_amdgcn_mfma_f32_16x16x32_f16(u.fr[0], bfrag[n][0], acc[n], 0, 0, 0);
                acc[n] = __builtin_amdgcn_mfma_f32_16x16x32_f16(u.fr[1], bfrag[n][1], acc[n], 0, 0, 0);
            }

            // per-tile epilogue: relu + w3 (packed f32), DPP row reduce,
            // then fold the r-select immediately (1 live reg per tile)
            f32x2 p01 = {0.f, 0.f}, p23 = {0.f, 0.f};
            #pragma unroll
            for (int n = 0; n < 4; ++n) {
                f32x2 lo = {acc[n][0], acc[n][1]};
                f32x2 hi = {acc[n][2], acc[n][3]};
                lo = __builtin_elementwise_max(lo, f32x2{0.f, 0.f});
                hi = __builtin_elementwise_max(hi, f32x2{0.f, 0.f});
                f32x2 wq = {w3v[n], w3v[n]};
                p01 += lo * wq;
                p23 += hi * wq;
            }
            float u0 = row_reduce16(p01[0]);
            float u1 = row_reduce16(p01[1]);
            float u2 = row_reduce16(p23[0]);
            float u3 = row_reduce16(p23[1]);
            float v01 = (nl & 1) ? u1 : u0;
            float v23 = (nl & 1) ? u3 : u2;
            ur[t] = (nl & 2) ? v23 : v01;
        }

        // send = ur[(nl>>2)&3]; final pull lands element e's u on lane e&63
        float s01  = (nl & 4) ? ur[1] : ur[0];
        float s23  = (nl & 4) ? ur[3] : ur[2];
        float send = (nl & 8) ? s23 : s01;
        float u_raw = __builtin_bit_cast(float,
            __builtin_amdgcn_ds_bpermute(srcb, __builtin_bit_cast(int, send)));

        float dx = fmaf(cdx, u_raw, base_dx);
        out[e]            = dx;
        out[2 * BTOT + e] = -dx;
    }
}

extern "C" void kernel_launch(void* const* d_in, const int* in_sizes, int n_in,
                              void* d_out, int out_size, void* d_ws, size_t ws_size,
                              hipStream_t stream) {
    const float* x  = (const float*)d_in[0];
    const float* y  = (const float*)d_in[1];
    const float* ex = (const float*)d_in[2];
    const float* ey = (const float*)d_in[3];
    const float* W1 = (const float*)d_in[4];
    const float* b1 = (const float*)d_in[5];
    const float* W2 = (const float*)d_in[6];
    const float* b2 = (const float*)d_in[7];
    const float* W3 = (const float*)d_in[8];
    float* out = (float*)d_out;
    unsigned char* ws = (unsigned char*)d_ws;

    setup_kernel<<<1, 256, 0, stream>>>(W1, b1, W2, b2, W3, ws);
    // 1024 blocks x 4 waves = 4 blocks/CU resident, grid-stride (R6 assignment)
    netc_kernel<<<1024, 256, 0, stream>>>(x, y, ex, ey, ws, out);
}